// Round 12
// baseline (82.668 us; speedup 1.0000x reference)
//
#include <hip/hip_runtime.h>

// ---------------------------------------------------------------------------
// LMU fused cell on MI355X (gfx950).  Round 12: TLP-max (32 waves/CU).
//   new_h = sigmoid([x|h|m] @ [Wx|Wh|Wm@AT]^T + u*(Wm@BT)^T)
//   new_m = m @ AT^T + u*BT^T     u = [x|h|m].e  (f32 exact, in prep)
// K0 lmu_wpack: weights -> bf16 B-layout [kk][n][8]; Wm2=Wm@AT; wu=Wm@BT.
// K1 lmu_prep:  x|h|m f32 -> one bf16 A-pack [16384][896] + u[16384] f32.
// K2 lmu_gemm:  BM=64 BN=64, 256 thr / 4 waves (wave 32x32), LDS 16KB
//   single-buffered, __launch_bounds__(256,8) -> VGPR<=64 -> 8 blocks/CU,
//   grid 2048 = 256 M x 8 N = exactly one uniform residency round.
//   18 chunks/block: 14 new_h (BK=64) + epilogue-h + 4 new_m (32-col share,
//   acc reused) + epilogue-m.  stage -> bar -> mma -> bar per chunk.
// ---------------------------------------------------------------------------

typedef __bf16 bf16;
typedef bf16  bf16x8 __attribute__((ext_vector_type(8)));
typedef float f32x4  __attribute__((ext_vector_type(4)));
typedef unsigned short u16;

#define BATCH 16384
// ws offsets (u16 units)
#define WPACK 0            // [896/8][512][8] = 458752  (kk>=80 = Wm@AT)
#define ATPACK 458752      // [256/8][256][8] = 65536
#define WUOFF 524288       // 512 f32  (1024 u16)
#define UOFF  525312       // 16384 f32 (32768 u16)
#define APACK 558080       // 16384*896 u16
// end: 15,238,144 u16 = ~30.5 MB

#define PACK_ITEMS 393728  // 327680 + 65536 + 512
#define PACK_BLOCKS 1538
#define WM2_BLOCKS 128

__device__ __forceinline__ u16 f2bf(float f) {
  unsigned u = __builtin_bit_cast(unsigned, f);
  u += 0x7FFFu + ((u >> 16) & 1u);   // RNE
  return (u16)(u >> 16);
}

__device__ __forceinline__ void gload16(const u16* g, u16* l) {
  __builtin_amdgcn_global_load_lds(
      (const __attribute__((address_space(1))) unsigned int*)g,
      (__attribute__((address_space(3))) unsigned int*)l, 16, 0, 0);
}

// ---------------- K0: merged weight prep (validated R8-R11) -----------------
__global__ __launch_bounds__(256) void lmu_wpack(
    const float* __restrict__ Wx, const float* __restrict__ Wh,
    const float* __restrict__ Wm, const float* __restrict__ AT,
    const float* __restrict__ BT, u16* __restrict__ ws) {
  __shared__ float wmt[16 * 256];
  const int bx = blockIdx.x;
  if (bx < PACK_BLOCKS) {
    int i = bx * 256 + threadIdx.x;
    if (i < 327680) {                     // Wall^T[k][n], k<640
      int j = i & 7, rest = i >> 3;
      int n = rest & 511, kk = rest >> 9;
      int k = kk * 8 + j;
      float v = (k < 128) ? Wx[n * 128 + k] : Wh[n * 512 + (k - 128)];
      ws[WPACK + i] = f2bf(v);
    } else if (i < 393216) {              // atpack[kk][d][j] = AT[d][kk*8+j]
      int t = i - 327680;
      int j = t & 7, rest = t >> 3;
      int d = rest & 255, kk = rest >> 8;
      ws[ATPACK + t] = f2bf(AT[d * 256 + kk * 8 + j]);
    } else if (i < PACK_ITEMS) {          // wu[n] = dot(Wm[n,:], BT)
      int n = i - 393216;
      float s = 0.f;
      for (int k = 0; k < 256; k += 4) {
        float4 wv = *(const float4*)(Wm + (size_t)n * 256 + k);
        float4 bv = *(const float4*)(BT + k);
        s += wv.x * bv.x + wv.y * bv.y + wv.z * bv.z + wv.w * bv.w;
      }
      ((float*)(ws + WUOFF))[n] = s;
    }
  } else {                                // Wm2 = Wm @ AT (16r x 64d tiles)
    const int wq = bx - PACK_BLOCKS;
    const int t = threadIdx.x;
    const int nb = (wq & 31) * 16, db = (wq >> 5) * 64;
#pragma unroll
    for (int it = 0; it < 4; ++it) {
      int f = it * 256 + t;
      float4 v = *(const float4*)(Wm + (size_t)(nb + (f >> 6)) * 256 + (f & 63) * 4);
      *(float4*)(wmt + (f >> 6) * 256 + (f & 63) * 4) = v;
    }
    __syncthreads();
    const int d = db + (t & 63);
    const int nn = (t >> 6) * 4;
    float acc[4] = {0.f, 0.f, 0.f, 0.f};
    for (int k = 0; k < 256; ++k) {
      float atv = AT[(size_t)k * 256 + d];
#pragma unroll
      for (int i2 = 0; i2 < 4; ++i2) acc[i2] += wmt[(nn + i2) * 256 + k] * atv;
    }
    const int kk = 80 + (d >> 3), j = d & 7;
#pragma unroll
    for (int i2 = 0; i2 < 4; ++i2)
      ws[WPACK + ((size_t)kk * 512 + (nb + nn + i2)) * 8 + j] = f2bf(acc[i2]);
  }
}

// ---------------- K1: A-pack [row][896] bf16 + u (f32 exact, validated) -----
__global__ __launch_bounds__(256) void lmu_prep(
    const float* __restrict__ x, const float* __restrict__ h,
    const float* __restrict__ m, const float* __restrict__ ex,
    const float* __restrict__ eh, const float* __restrict__ em,
    u16* __restrict__ ws) {
  const int lane = threadIdx.x & 63;
  const int row  = blockIdx.x * 4 + (threadIdx.x >> 6);
  u16* ap = ws + APACK + (size_t)row * 896;
  float s = 0.f;
#pragma unroll
  for (int j = 0; j < 4; ++j) {
    int slot = j * 64 + lane;
    if (slot < 224) {
      float4 a, e;
      if (slot < 32)       { int c = slot * 4;
        a = *(const float4*)(x + (size_t)row * 128 + c); e = *(const float4*)(ex + c); }
      else if (slot < 160) { int c = (slot - 32) * 4;
        a = *(const float4*)(h + (size_t)row * 512 + c); e = *(const float4*)(eh + c); }
      else                 { int c = (slot - 160) * 4;
        a = *(const float4*)(m + (size_t)row * 256 + c); e = *(const float4*)(em + c); }
      s += a.x * e.x + a.y * e.y + a.z * e.z + a.w * e.w;
      unsigned long long pk =
          (unsigned long long)f2bf(a.x)
        | ((unsigned long long)f2bf(a.y) << 16)
        | ((unsigned long long)f2bf(a.z) << 32)
        | ((unsigned long long)f2bf(a.w) << 48);
      *(unsigned long long*)(ap + slot * 4) = pk;
    }
  }
#pragma unroll
  for (int d = 1; d < 64; d <<= 1) s += __shfl_xor(s, d);
  if (lane == 0) ((float*)(ws + UOFF))[row] = s;
}

// ---------------- K2: main GEMM ----------------------------------------------
// grid 2048 = 256 M-tiles x 8 N-slices; 256 thr, 4 waves (2M x 2N), 32x32/wave.
// LDS 16KB single-buffered: A [8kb][64r][8] = 4096 u16, B [8kk][64n][8] = 4096.
__global__ __launch_bounds__(256, 8) void lmu_gemm(
    const u16* __restrict__ ws, const float* __restrict__ BT,
    float* __restrict__ out) {
  __shared__ __align__(16) u16 smem[8192];
  const int tid  = threadIdx.x;
  const int lane = tid & 63;
  const int w    = tid >> 6;     // 0..3
  const int wr   = w >> 1;       // 0..1 : 32-row half
  const int wc   = w & 1;        // 0..1 : 32-col (new_h) / 16-col (new_m)
  const int lm   = lane & 15;
  const int kg   = lane >> 4;
  // 8 N-slices of one M-tile adjacent on one XCD
  const int bid  = blockIdx.x;
  const int xcd  = bid & 7;
  const int q    = bid >> 3;               // 0..255
  const int nsl  = q & 7;                  // 0..7
  const int mi   = xcd * 32 + (q >> 3);    // 0..255
  const int b0   = mi * 64;

  const u16* wpk = ws + WPACK;
  const u16* atp = ws + ATPACK;
  const u16* ap  = ws + APACK;
  const float* uf  = (const float*)(ws + UOFF);
  const float* wuf = (const float*)(ws + WUOFF);
  float* outm = out + (size_t)BATCH * 512;

  f32x4 acc[2][2];   // wave 32r x 32c
#pragma unroll
  for (int mt = 0; mt < 2; ++mt)
#pragma unroll
    for (int ct = 0; ct < 2; ++ct) acc[mt][ct] = (f32x4){0.f, 0.f, 0.f, 0.f};

  auto stageA = [&](int koff) {            // 64r x 64k -> [kb][r][8]
#pragma unroll
    for (int ph = 0; ph < 2; ++ph) {
      int i = ph * 256 + tid;
      gload16(ap + (size_t)(b0 + (i & 63)) * 896 + koff + (i >> 6) * 8, smem + i * 8);
    }
  };
  auto stageBh = [&](int c) {              // [kk][64n][8]
#pragma unroll
    for (int ph = 0; ph < 2; ++ph) {
      int i = ph * 256 + tid;
      gload16(wpk + ((size_t)(c * 8 + (i >> 6)) * 512 + nsl * 64 + (i & 63)) * 8,
              smem + 4096 + i * 8);
    }
  };
  auto stageBm = [&](int cm) {             // [kk][32n][8] (4KB, 1 load/thread)
    gload16(atp + ((size_t)(cm * 8 + (tid >> 5)) * 256 + nsl * 32 + (tid & 31)) * 8,
            smem + 4096 + tid * 8);
  };
  auto mma_h = [&]() {
#pragma unroll
    for (int ks = 0; ks < 2; ++ks) {
      const int kq = ks * 4 + kg;
      bf16x8 a[2], b[2];
#pragma unroll
      for (int mt = 0; mt < 2; ++mt)
        a[mt] = *(const bf16x8*)(smem + (kq * 64 + wr * 32 + mt * 16 + lm) * 8);
#pragma unroll
      for (int ct = 0; ct < 2; ++ct)
        b[ct] = *(const bf16x8*)(smem + 4096 + (kq * 64 + wc * 32 + ct * 16 + lm) * 8);
#pragma unroll
      for (int mt = 0; mt < 2; ++mt)
#pragma unroll
        for (int ct = 0; ct < 2; ++ct)
          acc[mt][ct] = __builtin_amdgcn_mfma_f32_16x16x32_bf16(a[mt], b[ct], acc[mt][ct], 0, 0, 0);
    }
  };
  auto mma_m = [&]() {
#pragma unroll
    for (int ks = 0; ks < 2; ++ks) {
      const int kq = ks * 4 + kg;
      bf16x8 a[2];
#pragma unroll
      for (int mt = 0; mt < 2; ++mt)
        a[mt] = *(const bf16x8*)(smem + (kq * 64 + wr * 32 + mt * 16 + lm) * 8);
      bf16x8 b = *(const bf16x8*)(smem + 4096 + (kq * 32 + wc * 16 + lm) * 8);
#pragma unroll
      for (int mt = 0; mt < 2; ++mt)
        acc[mt][0] = __builtin_amdgcn_mfma_f32_16x16x32_bf16(a[mt], b, acc[mt][0], 0, 0, 0);
    }
  };

  // ---- 14 new_h chunks ----
#pragma unroll 2
  for (int c = 0; c < 14; ++c) {
    stageA(c * 64);
    stageBh(c);
    __syncthreads();
    mma_h();
    __syncthreads();
  }
  // ---- epilogue new_h ----
  {
    float wuv[2];
#pragma unroll
    for (int ct = 0; ct < 2; ++ct) wuv[ct] = wuf[nsl * 64 + wc * 32 + ct * 16 + lm];
#pragma unroll
    for (int mt = 0; mt < 2; ++mt)
#pragma unroll
      for (int j = 0; j < 4; ++j) {
        int rl = wr * 32 + mt * 16 + kg * 4 + j;
        size_t row = (size_t)(b0 + rl);
        float uv = uf[row];
#pragma unroll
        for (int ct = 0; ct < 2; ++ct) {
          float v = acc[mt][ct][j] + uv * wuv[ct];
          out[row * 512 + nsl * 64 + wc * 32 + ct * 16 + lm] = 1.0f / (1.0f + __expf(-v));
        }
      }
  }
  // ---- 4 new_m chunks (32-col share, acc reused) ----
#pragma unroll
  for (int mt = 0; mt < 2; ++mt) acc[mt][0] = (f32x4){0.f, 0.f, 0.f, 0.f};
#pragma unroll 2
  for (int cm = 0; cm < 4; ++cm) {
    stageA(640 + cm * 64);
    stageBm(cm);
    __syncthreads();
    mma_m();
    __syncthreads();
  }
  // ---- epilogue new_m ----
  {
    const float btv = BT[nsl * 32 + wc * 16 + lm];
#pragma unroll
    for (int mt = 0; mt < 2; ++mt)
#pragma unroll
      for (int j = 0; j < 4; ++j) {
        int rl = wr * 32 + mt * 16 + kg * 4 + j;
        size_t row = (size_t)(b0 + rl);
        outm[row * 256 + nsl * 32 + wc * 16 + lm] = acc[mt][0][j] + uf[row] * btv;
      }
  }
}

extern "C" void kernel_launch(void* const* d_in, const int* in_sizes, int n_in,
                              void* d_out, int out_size, void* d_ws, size_t ws_size,
                              hipStream_t stream) {
  const float* x  = (const float*)d_in[0];
  const float* h  = (const float*)d_in[1];
  const float* m  = (const float*)d_in[2];
  const float* Wx = (const float*)d_in[3];
  const float* Wh = (const float*)d_in[4];
  const float* Wm = (const float*)d_in[5];
  const float* ex = (const float*)d_in[6];
  const float* eh = (const float*)d_in[7];
  const float* em = (const float*)d_in[8];
  const float* AT = (const float*)d_in[9];
  const float* BT = (const float*)d_in[10];
  float* out = (float*)d_out;
  u16* ws = (u16*)d_ws;   // uses ~30.5 MB

  lmu_wpack<<<PACK_BLOCKS + WM2_BLOCKS, 256, 0, stream>>>(Wx, Wh, Wm, AT, BT, ws);
  lmu_prep<<<BATCH / 4, 256, 0, stream>>>(x, h, m, ex, eh, em, ws);
  lmu_gemm<<<2048, 256, 0, stream>>>(ws, BT, out);
}

// Round 13
// 61.576 us; speedup vs baseline: 1.3425x; 1.3425x over previous
//
#include <hip/hip_runtime.h>

// ---------------------------------------------------------------------------
// LMU fused cell on MI355X (gfx950).  Round 13: consolidation of measured-best
// components.  gemm = R4 structure verbatim (40us measured) + dummy-S fix;
// prep = R12 vectorized (float4); wpack = merged single launch.
//   new_h = sigmoid([x|h|m] @ [Wx|Wh|Wm@AT]^T + u*(Wm@BT)^T)
//   new_m = m @ AT^T + u*BT^T     u = [x|h|m].e  (f32 exact, in prep)
// ---------------------------------------------------------------------------

typedef __bf16 bf16;
typedef bf16  bf16x8 __attribute__((ext_vector_type(8)));
typedef float f32x4  __attribute__((ext_vector_type(4)));
typedef unsigned short u16;

#define BATCH 16384
// ws offsets (u16 units)
#define WPACK 0            // [896/8][512][8] = 458752  (kk>=80 = Wm@AT)
#define ATPACK 458752      // [256/8][256][8] = 65536
#define WUOFF 524288       // 512 f32  (1024 u16)
#define UOFF  525312       // 16384 f32 (32768 u16)
#define APACK 558080       // 16384*896 u16
// end: 15,238,144 u16 = ~30.5 MB

#define PACK_ITEMS 393728  // 327680 + 65536 + 512
#define PACK_BLOCKS 1538
#define WM2_BLOCKS 128

__device__ __forceinline__ u16 f2bf(float f) {
  unsigned u = __builtin_bit_cast(unsigned, f);
  u += 0x7FFFu + ((u >> 16) & 1u);   // RNE
  return (u16)(u >> 16);
}

__device__ __forceinline__ void gload16(const u16* g, u16* l) {
  __builtin_amdgcn_global_load_lds(
      (const __attribute__((address_space(1))) unsigned int*)g,
      (__attribute__((address_space(3))) unsigned int*)l, 16, 0, 0);
}

// ---------------- K0: merged weight prep (validated R8-R12) -----------------
__global__ __launch_bounds__(256) void lmu_wpack(
    const float* __restrict__ Wx, const float* __restrict__ Wh,
    const float* __restrict__ Wm, const float* __restrict__ AT,
    const float* __restrict__ BT, u16* __restrict__ ws) {
  __shared__ float wmt[16 * 256];
  const int bx = blockIdx.x;
  if (bx < PACK_BLOCKS) {
    int i = bx * 256 + threadIdx.x;
    if (i < 327680) {                     // Wall^T[k][n], k<640
      int j = i & 7, rest = i >> 3;
      int n = rest & 511, kk = rest >> 9;
      int k = kk * 8 + j;
      float v = (k < 128) ? Wx[n * 128 + k] : Wh[n * 512 + (k - 128)];
      ws[WPACK + i] = f2bf(v);
    } else if (i < 393216) {              // atpack[kk][d][j] = AT[d][kk*8+j]
      int t = i - 327680;
      int j = t & 7, rest = t >> 3;
      int d = rest & 255, kk = rest >> 8;
      ws[ATPACK + t] = f2bf(AT[d * 256 + kk * 8 + j]);
    } else if (i < PACK_ITEMS) {          // wu[n] = dot(Wm[n,:], BT)
      int n = i - 393216;
      float s = 0.f;
      for (int k = 0; k < 256; k += 4) {
        float4 wv = *(const float4*)(Wm + (size_t)n * 256 + k);
        float4 bv = *(const float4*)(BT + k);
        s += wv.x * bv.x + wv.y * bv.y + wv.z * bv.z + wv.w * bv.w;
      }
      ((float*)(ws + WUOFF))[n] = s;
    }
  } else {                                // Wm2 = Wm @ AT (16r x 64d tiles)
    const int wq = bx - PACK_BLOCKS;
    const int t = threadIdx.x;
    const int nb = (wq & 31) * 16, db = (wq >> 5) * 64;
#pragma unroll
    for (int it = 0; it < 4; ++it) {
      int f = it * 256 + t;
      float4 v = *(const float4*)(Wm + (size_t)(nb + (f >> 6)) * 256 + (f & 63) * 4);
      *(float4*)(wmt + (f >> 6) * 256 + (f & 63) * 4) = v;
    }
    __syncthreads();
    const int d = db + (t & 63);
    const int nn = (t >> 6) * 4;
    float acc[4] = {0.f, 0.f, 0.f, 0.f};
    for (int k = 0; k < 256; ++k) {
      float atv = AT[(size_t)k * 256 + d];
#pragma unroll
      for (int i2 = 0; i2 < 4; ++i2) acc[i2] += wmt[(nn + i2) * 256 + k] * atv;
    }
    const int kk = 80 + (d >> 3), j = d & 7;
#pragma unroll
    for (int i2 = 0; i2 < 4; ++i2)
      ws[WPACK + ((size_t)kk * 512 + (nb + nn + i2)) * 8 + j] = f2bf(acc[i2]);
  }
}

// ---------------- K1: A-pack [row][896] bf16 + u (f32 exact, R12) -----------
__global__ __launch_bounds__(256) void lmu_prep(
    const float* __restrict__ x, const float* __restrict__ h,
    const float* __restrict__ m, const float* __restrict__ ex,
    const float* __restrict__ eh, const float* __restrict__ em,
    u16* __restrict__ ws) {
  const int lane = threadIdx.x & 63;
  const int row  = blockIdx.x * 4 + (threadIdx.x >> 6);
  u16* ap = ws + APACK + (size_t)row * 896;
  float s = 0.f;
#pragma unroll
  for (int j = 0; j < 4; ++j) {
    int slot = j * 64 + lane;
    if (slot < 224) {
      float4 a, e;
      if (slot < 32)       { int c = slot * 4;
        a = *(const float4*)(x + (size_t)row * 128 + c); e = *(const float4*)(ex + c); }
      else if (slot < 160) { int c = (slot - 32) * 4;
        a = *(const float4*)(h + (size_t)row * 512 + c); e = *(const float4*)(eh + c); }
      else                 { int c = (slot - 160) * 4;
        a = *(const float4*)(m + (size_t)row * 256 + c); e = *(const float4*)(em + c); }
      s += a.x * e.x + a.y * e.y + a.z * e.z + a.w * e.w;
      unsigned long long pk =
          (unsigned long long)f2bf(a.x)
        | ((unsigned long long)f2bf(a.y) << 16)
        | ((unsigned long long)f2bf(a.z) << 32)
        | ((unsigned long long)f2bf(a.w) << 48);
      *(unsigned long long*)(ap + slot * 4) = pk;
    }
  }
#pragma unroll
  for (int d = 1; d < 64; d <<= 1) s += __shfl_xor(s, d);
  if (lane == 0) ((float*)(ws + UOFF))[row] = s;
}

// ---------------- K2: main GEMM (R4 structure verbatim) ---------------------
// grid 512 = 128 M-tiles x 4 N-slices; 512 thr; LDS 80KB (2 x 40KB dbuf).
// per 40KB buffer: A [8kb][128r][8] @0, B [8kk][128n][8] @8192 u16,
//                  S [8kk][64n][8] @16384 u16 (staged only for c>=10).
__global__ __launch_bounds__(512, 4) void lmu_gemm(
    const u16* __restrict__ ws, const float* __restrict__ BT,
    float* __restrict__ out) {
  __shared__ __align__(16) u16 smem[2 * 20480];
  const int tid  = threadIdx.x;
  const int lane = tid & 63;
  const int w    = tid >> 6;     // 0..7
  const int wr   = w >> 1;       // 0..3 (32-row slice)
  const int wc   = w & 1;        // 0..1 (64-col slice)
  const int lm   = lane & 15;
  const int kg   = lane >> 4;
  const int bid  = blockIdx.x;
  const int mi   = (bid & 7) | ((bid >> 5) << 3);  // same-m N-slices -> same XCD
  const int nsl  = (bid >> 3) & 3;
  const int b0   = mi * 128;

  const u16* apack = ws + APACK;
  const u16* wpk   = ws + WPACK;
  const u16* atp   = ws + ATPACK;

  f32x4 acc[2][4];    // new_h: 2 Mfrag x 4 Nfrag (32r x 64c per wave)
  f32x4 acc2[2][2];   // new_m: 2 Mfrag x 2 Nfrag (32c per wave)
#pragma unroll
  for (int mt = 0; mt < 2; ++mt) {
#pragma unroll
    for (int ct = 0; ct < 4; ++ct) acc[mt][ct] = (f32x4){0.f, 0.f, 0.f, 0.f};
#pragma unroll
    for (int ct = 0; ct < 2; ++ct) acc2[mt][ct] = (f32x4){0.f, 0.f, 0.f, 0.f};
  }

  auto stage = [&](int c) {
    u16* buf = smem + (c & 1) * 20480;
#pragma unroll
    for (int ph = 0; ph < 2; ++ph) {           // A chunk: 16KB
      int i = ph * 512 + tid;
      int kb = i >> 7, r = i & 127;
      gload16(apack + (size_t)(b0 + r) * 896 + c * 64 + kb * 8, buf + i * 8);
    }
#pragma unroll
    for (int ph = 0; ph < 2; ++ph) {           // B chunk: 16KB
      int i = ph * 512 + tid;
      int kk = i >> 7, n = i & 127;
      gload16(wpk + ((size_t)(c * 8 + kk) * 512 + nsl * 128 + n) * 8,
              buf + 8192 + i * 8);
    }
    if (c >= 10) {                              // side B (atpack): 8KB
      int kk = tid >> 6, n = tid & 63;
      gload16(atp + ((size_t)((c - 10) * 8 + kk) * 256 + nsl * 64 + n) * 8,
              buf + 16384 + tid * 8);
    }
  };

  auto mma = [&](int c) {
    const u16* buf = smem + (c & 1) * 20480;
#pragma unroll
    for (int ks = 0; ks < 2; ++ks) {
      const int kq = ks * 4 + kg;
      bf16x8 a[2];
#pragma unroll
      for (int mt = 0; mt < 2; ++mt)
        a[mt] = *(const bf16x8*)(buf + (kq * 128 + wr * 32 + mt * 16 + lm) * 8);
#pragma unroll
      for (int ct = 0; ct < 4; ++ct) {
        bf16x8 b = *(const bf16x8*)(buf + 8192 + (kq * 128 + wc * 64 + ct * 16 + lm) * 8);
#pragma unroll
        for (int mt = 0; mt < 2; ++mt)
          acc[mt][ct] = __builtin_amdgcn_mfma_f32_16x16x32_bf16(a[mt], b, acc[mt][ct], 0, 0, 0);
      }
      if (c >= 10) {
#pragma unroll
        for (int ct = 0; ct < 2; ++ct) {
          bf16x8 b = *(const bf16x8*)(buf + 16384 + (kq * 64 + wc * 32 + ct * 16 + lm) * 8);
#pragma unroll
          for (int mt = 0; mt < 2; ++mt)
            acc2[mt][ct] = __builtin_amdgcn_mfma_f32_16x16x32_bf16(a[mt], b, acc2[mt][ct], 0, 0, 0);
        }
      }
    }
  };

  stage(0);
  __syncthreads();
#pragma unroll
  for (int c = 0; c < 14; ++c) {
    if (c < 13) stage(c + 1);   // issue next-chunk loads first (overlap)
    mma(c);                     // compute current from LDS
    __syncthreads();            // drains vmcnt -> next buffer ready
  }

  // ---- epilogue ----
  const float* uf  = (const float*)(ws + UOFF);
  const float* wuf = (const float*)(ws + WUOFF);
  float wuv[4], btv[2];
#pragma unroll
  for (int ct = 0; ct < 4; ++ct) wuv[ct] = wuf[nsl * 128 + wc * 64 + ct * 16 + lm];
#pragma unroll
  for (int ct = 0; ct < 2; ++ct) btv[ct] = BT[nsl * 64 + wc * 32 + ct * 16 + lm];
  float* outm = out + (size_t)BATCH * 512;
#pragma unroll
  for (int mt = 0; mt < 2; ++mt)
#pragma unroll
    for (int j = 0; j < 4; ++j) {
      int rl = wr * 32 + mt * 16 + kg * 4 + j;
      size_t row = (size_t)(b0 + rl);
      float uv = uf[row];
#pragma unroll
      for (int ct = 0; ct < 4; ++ct) {
        float v = acc[mt][ct][j] + uv * wuv[ct];
        out[row * 512 + nsl * 128 + wc * 64 + ct * 16 + lm] = 1.0f / (1.0f + __expf(-v));
      }
#pragma unroll
      for (int ct = 0; ct < 2; ++ct)
        outm[row * 256 + nsl * 64 + wc * 32 + ct * 16 + lm] = acc2[mt][ct][j] + uv * btv[ct];
    }
}

extern "C" void kernel_launch(void* const* d_in, const int* in_sizes, int n_in,
                              void* d_out, int out_size, void* d_ws, size_t ws_size,
                              hipStream_t stream) {
  const float* x  = (const float*)d_in[0];
  const float* h  = (const float*)d_in[1];
  const float* m  = (const float*)d_in[2];
  const float* Wx = (const float*)d_in[3];
  const float* Wh = (const float*)d_in[4];
  const float* Wm = (const float*)d_in[5];
  const float* ex = (const float*)d_in[6];
  const float* eh = (const float*)d_in[7];
  const float* em = (const float*)d_in[8];
  const float* AT = (const float*)d_in[9];
  const float* BT = (const float*)d_in[10];
  float* out = (float*)d_out;
  u16* ws = (u16*)d_ws;   // uses ~30.5 MB

  lmu_wpack<<<PACK_BLOCKS + WM2_BLOCKS, 256, 0, stream>>>(Wx, Wh, Wm, AT, BT, ws);
  lmu_prep<<<BATCH / 4, 256, 0, stream>>>(x, h, m, ex, eh, em, ws);
  lmu_gemm<<<512, 512, 0, stream>>>(ws, BT, out);
}

// Round 14
// 53.035 us; speedup vs baseline: 1.5587x; 1.1610x over previous
//
#include <hip/hip_runtime.h>

// ---------------------------------------------------------------------------
// LMU fused cell on MI355X (gfx950).  Round 14: counted-vmcnt 3-buffer pipe.
//   new_h = sigmoid([x|h|m] @ [Wx|Wh|Wm@AT]^T + u*(Wm@BT)^T)
//   new_m = m @ AT^T + u*BT^T     u = [x|h|m].e  (f32 exact, in prep)
// K0 lmu_pre: merged weight-pack + Wm2 + wu + A-pack/u prep (one dispatch).
// K1 lmu_gemm: R13 geometry (512 blk x 512 thr, BM=128 BN=128, 2 blk/CU) but
//   BK=32 x 28 chunks, 3 x 24KB LDS buffers, uniform {A,B[,S]} loads/thread,
//   raw s_barrier + counted s_waitcnt vmcnt(2/3/0) -- loads span barriers.
// ---------------------------------------------------------------------------

typedef __bf16 bf16;
typedef bf16  bf16x8 __attribute__((ext_vector_type(8)));
typedef float f32x4  __attribute__((ext_vector_type(4)));
typedef unsigned short u16;

#define BATCH 16384
// ws offsets (u16 units)
#define WPACK 0            // [896/8][512][8] = 458752  (kk>=80 = Wm@AT)
#define ATPACK 458752      // [256/8][256][8] = 65536
#define WUOFF 524288       // 512 f32  (1024 u16)
#define UOFF  525312       // 16384 f32 (32768 u16)
#define APACK 558080       // 16384*896 u16
// end: 15,238,144 u16 = ~30.5 MB

#define PACK_ITEMS 393728  // 327680 + 65536 + 512
#define PACK_BLOCKS 1538
#define WM2_BLOCKS 128
#define PREP_BLOCKS 4096   // 4 rows/block

__device__ __forceinline__ u16 f2bf(float f) {
  unsigned u = __builtin_bit_cast(unsigned, f);
  u += 0x7FFFu + ((u >> 16) & 1u);   // RNE
  return (u16)(u >> 16);
}

__device__ __forceinline__ void gload16(const u16* g, u16* l) {
  __builtin_amdgcn_global_load_lds(
      (const __attribute__((address_space(1))) unsigned int*)g,
      (__attribute__((address_space(3))) unsigned int*)l, 16, 0, 0);
}

// ---------------- K0: merged prologue (wpack + wm2 + prep) ------------------
__global__ __launch_bounds__(256) void lmu_pre(
    const float* __restrict__ Wx, const float* __restrict__ Wh,
    const float* __restrict__ Wm, const float* __restrict__ AT,
    const float* __restrict__ BT, const float* __restrict__ x,
    const float* __restrict__ h, const float* __restrict__ m,
    const float* __restrict__ ex, const float* __restrict__ eh,
    const float* __restrict__ em, u16* __restrict__ ws) {
  __shared__ float wmt[16 * 256];
  const int bx = blockIdx.x;
  if (bx < PACK_BLOCKS) {
    int i = bx * 256 + threadIdx.x;
    if (i < 327680) {                     // Wall^T[k][n], k<640
      int j = i & 7, rest = i >> 3;
      int n = rest & 511, kk = rest >> 9;
      int k = kk * 8 + j;
      float v = (k < 128) ? Wx[n * 128 + k] : Wh[n * 512 + (k - 128)];
      ws[WPACK + i] = f2bf(v);
    } else if (i < 393216) {              // atpack[kk][d][j] = AT[d][kk*8+j]
      int t = i - 327680;
      int j = t & 7, rest = t >> 3;
      int d = rest & 255, kk = rest >> 8;
      ws[ATPACK + t] = f2bf(AT[d * 256 + kk * 8 + j]);
    } else if (i < PACK_ITEMS) {          // wu[n] = dot(Wm[n,:], BT)
      int n = i - 393216;
      float s = 0.f;
      for (int k = 0; k < 256; k += 4) {
        float4 wv = *(const float4*)(Wm + (size_t)n * 256 + k);
        float4 bv = *(const float4*)(BT + k);
        s += wv.x * bv.x + wv.y * bv.y + wv.z * bv.z + wv.w * bv.w;
      }
      ((float*)(ws + WUOFF))[n] = s;
    }
  } else if (bx < PACK_BLOCKS + WM2_BLOCKS) {   // Wm2 = Wm @ AT
    const int wq = bx - PACK_BLOCKS;
    const int t = threadIdx.x;
    const int nb = (wq & 31) * 16, db = (wq >> 5) * 64;
#pragma unroll
    for (int it = 0; it < 4; ++it) {
      int f = it * 256 + t;
      float4 v = *(const float4*)(Wm + (size_t)(nb + (f >> 6)) * 256 + (f & 63) * 4);
      *(float4*)(wmt + (f >> 6) * 256 + (f & 63) * 4) = v;
    }
    __syncthreads();
    const int d = db + (t & 63);
    const int nn = (t >> 6) * 4;
    float acc[4] = {0.f, 0.f, 0.f, 0.f};
    for (int k = 0; k < 256; ++k) {
      float atv = AT[(size_t)k * 256 + d];
#pragma unroll
      for (int i2 = 0; i2 < 4; ++i2) acc[i2] += wmt[(nn + i2) * 256 + k] * atv;
    }
    const int kk = 80 + (d >> 3), j = d & 7;
#pragma unroll
    for (int i2 = 0; i2 < 4; ++i2)
      ws[WPACK + ((size_t)kk * 512 + (nb + nn + i2)) * 8 + j] = f2bf(acc[i2]);
  } else {                                      // A-pack + u (f32 exact)
    const int lane = threadIdx.x & 63;
    const int row  = (bx - PACK_BLOCKS - WM2_BLOCKS) * 4 + (threadIdx.x >> 6);
    u16* ap = ws + APACK + (size_t)row * 896;
    float s = 0.f;
#pragma unroll
    for (int j = 0; j < 4; ++j) {
      int slot = j * 64 + lane;
      if (slot < 224) {
        float4 a, e;
        if (slot < 32)       { int c = slot * 4;
          a = *(const float4*)(x + (size_t)row * 128 + c); e = *(const float4*)(ex + c); }
        else if (slot < 160) { int c = (slot - 32) * 4;
          a = *(const float4*)(h + (size_t)row * 512 + c); e = *(const float4*)(eh + c); }
        else                 { int c = (slot - 160) * 4;
          a = *(const float4*)(m + (size_t)row * 256 + c); e = *(const float4*)(em + c); }
        s += a.x * e.x + a.y * e.y + a.z * e.z + a.w * e.w;
        unsigned long long pk =
            (unsigned long long)f2bf(a.x)
          | ((unsigned long long)f2bf(a.y) << 16)
          | ((unsigned long long)f2bf(a.z) << 32)
          | ((unsigned long long)f2bf(a.w) << 48);
        *(unsigned long long*)(ap + slot * 4) = pk;
      }
    }
#pragma unroll
    for (int d = 1; d < 64; d <<= 1) s += __shfl_xor(s, d);
    if (lane == 0) ((float*)(ws + UOFF))[row] = s;
  }
}

// ---------------- K1: main GEMM, counted-vmcnt 3-buffer ---------------------
// grid 512 = 128 M-tiles x 4 N-slices; 512 thr; LDS 3 x 24KB.
// buffer (12288 u16): A [4kb][128r][8] @0, B [4kk][128n][8] @4096,
//                     S [4kk][128(dup64)][8] @8192 (chunks >= 20 only).
__global__ __launch_bounds__(512, 4) void lmu_gemm(
    const u16* __restrict__ ws, const float* __restrict__ BT,
    float* __restrict__ out) {
  __shared__ __align__(16) u16 smem[36864];
  const int tid  = threadIdx.x;
  const int lane = tid & 63;
  const int w    = tid >> 6;     // 0..7
  const int wr   = w >> 1;       // 0..3 (32-row slice)
  const int wc   = w & 1;        // 0..1 (64-col slice)
  const int lm   = lane & 15;
  const int kg   = lane >> 4;    // 0..3
  const int bid  = blockIdx.x;
  const int mi   = (bid & 7) | ((bid >> 5) << 3);  // same-M N-slices -> same XCD
  const int nsl  = (bid >> 3) & 3;
  const int b0   = mi * 128;

  const u16* apack = ws + APACK;
  const u16* wpk   = ws + WPACK;
  const u16* atp   = ws + ATPACK;
  const float* uf  = (const float*)(ws + UOFF);
  const float* wuf = (const float*)(ws + WUOFF);

  // epilogue constants loaded BEFORE stage(0) so loop vmcnt counts stay exact
  float wuv[4], btv[2];
#pragma unroll
  for (int ct = 0; ct < 4; ++ct) wuv[ct] = wuf[nsl * 128 + wc * 64 + ct * 16 + lm];
#pragma unroll
  for (int ct = 0; ct < 2; ++ct) btv[ct] = BT[nsl * 64 + wc * 32 + ct * 16 + lm];

  f32x4 acc[2][4];    // new_h: 2 Mfrag x 4 Nfrag (32r x 64c per wave)
  f32x4 acc2[2][2];   // new_m: 2 Mfrag x 2 Nfrag (32c per wave)
#pragma unroll
  for (int mt = 0; mt < 2; ++mt) {
#pragma unroll
    for (int ct = 0; ct < 4; ++ct) acc[mt][ct] = (f32x4){0.f, 0.f, 0.f, 0.f};
#pragma unroll
    for (int ct = 0; ct < 2; ++ct) acc2[mt][ct] = (f32x4){0.f, 0.f, 0.f, 0.f};
  }

  auto stage = [&](int c, u16* buf) {
    // A: 128r x 32k = 8KB -> 1 load/thread (LDS linear in tid, wave-uniform)
    gload16(apack + (size_t)(b0 + (tid & 127)) * 896 + c * 32 + (tid >> 7) * 8,
            buf + tid * 8);
    // B: 4kk x 128n = 8KB -> 1 load/thread
    gload16(wpk + ((size_t)(c * 4 + (tid >> 7)) * 512 + nsl * 128 + (tid & 127)) * 8,
            buf + 4096 + tid * 8);
    if (c >= 20) {   // S: 4kk x 64n duplicated to 128 -> 1 load/thread
      int cm = c - 20;
      gload16(atp + ((size_t)(cm * 4 + (tid >> 7)) * 256 + nsl * 64 + (tid & 63)) * 8,
              buf + 8192 + tid * 8);
    }
  };

  auto mma = [&](const u16* buf, int c) {
    const int kq = kg;
    bf16x8 a[2], b[4];
#pragma unroll
    for (int mt = 0; mt < 2; ++mt)
      a[mt] = *(const bf16x8*)(buf + (kq * 128 + wr * 32 + mt * 16 + lm) * 8);
#pragma unroll
    for (int ct = 0; ct < 4; ++ct)
      b[ct] = *(const bf16x8*)(buf + 4096 + (kq * 128 + wc * 64 + ct * 16 + lm) * 8);
#pragma unroll
    for (int mt = 0; mt < 2; ++mt)
#pragma unroll
      for (int ct = 0; ct < 4; ++ct)
        acc[mt][ct] = __builtin_amdgcn_mfma_f32_16x16x32_bf16(a[mt], b[ct], acc[mt][ct], 0, 0, 0);
    if (c >= 20) {
#pragma unroll
      for (int ct = 0; ct < 2; ++ct) {
        bf16x8 s = *(const bf16x8*)(buf + 8192 + (kq * 128 + wc * 32 + ct * 16 + lm) * 8);
#pragma unroll
        for (int mt = 0; mt < 2; ++mt)
          acc2[mt][ct] = __builtin_amdgcn_mfma_f32_16x16x32_bf16(a[mt], s, acc2[mt][ct], 0, 0, 0);
      }
    }
  };

  u16 *p0 = smem, *p1 = smem + 12288, *p2 = smem + 24576;

  // prologue: fill 2 chunks; wait chunk 0 (2 loads in flight for chunk 1)
  stage(0, p0);
  stage(1, p1);
  asm volatile("s_waitcnt vmcnt(2)" ::: "memory");
  __builtin_amdgcn_s_barrier();

#pragma unroll 1
  for (int c = 0; c < 28; ++c) {
    if (c + 2 < 28) stage(c + 2, p2);      // loads span the coming barrier
    mma(p0, c);
    if (c < 27) {
      // wait for chunk c+1 complete; chunk c+2's loads remain outstanding
      if (c < 18)      asm volatile("s_waitcnt vmcnt(2)" ::: "memory");
      else if (c < 26) asm volatile("s_waitcnt vmcnt(3)" ::: "memory");
      else             asm volatile("s_waitcnt vmcnt(0)" ::: "memory");
      __builtin_amdgcn_s_barrier();
    }
    u16* t0 = p0; p0 = p1; p1 = p2; p2 = t0;   // rotate buffers
  }

  // ---- epilogue ----
  float* outm = out + (size_t)BATCH * 512;
#pragma unroll
  for (int mt = 0; mt < 2; ++mt)
#pragma unroll
    for (int j = 0; j < 4; ++j) {
      int rl = wr * 32 + mt * 16 + kg * 4 + j;
      size_t row = (size_t)(b0 + rl);
      float uv = uf[row];
#pragma unroll
      for (int ct = 0; ct < 4; ++ct) {
        float v = acc[mt][ct][j] + uv * wuv[ct];
        out[row * 512 + nsl * 128 + wc * 64 + ct * 16 + lm] = 1.0f / (1.0f + __expf(-v));
      }
#pragma unroll
      for (int ct = 0; ct < 2; ++ct)
        outm[row * 256 + nsl * 64 + wc * 32 + ct * 16 + lm] = acc2[mt][ct][j] + uv * btv[ct];
    }
}

extern "C" void kernel_launch(void* const* d_in, const int* in_sizes, int n_in,
                              void* d_out, int out_size, void* d_ws, size_t ws_size,
                              hipStream_t stream) {
  const float* x  = (const float*)d_in[0];
  const float* h  = (const float*)d_in[1];
  const float* m  = (const float*)d_in[2];
  const float* Wx = (const float*)d_in[3];
  const float* Wh = (const float*)d_in[4];
  const float* Wm = (const float*)d_in[5];
  const float* ex = (const float*)d_in[6];
  const float* eh = (const float*)d_in[7];
  const float* em = (const float*)d_in[8];
  const float* AT = (const float*)d_in[9];
  const float* BT = (const float*)d_in[10];
  float* out = (float*)d_out;
  u16* ws = (u16*)d_ws;   // uses ~30.5 MB

  lmu_pre<<<PACK_BLOCKS + WM2_BLOCKS + PREP_BLOCKS, 256, 0, stream>>>(
      Wx, Wh, Wm, AT, BT, x, h, m, ex, eh, em, ws);
  lmu_gemm<<<512, 512, 0, stream>>>(ws, BT, out);
}